// Round 3
// baseline (1015.921 us; speedup 1.0000x reference)
//
#include <hip/hip_runtime.h>
#include <hip/hip_bf16.h>
#include <float.h>
#include <math.h>

#define NQ    64      // batch / query count
#define DF    256     // feature dim
#define CC    345     // class dim
#define KSF   8       // 256/32 k-steps
#define KSC   11      // ceil(345/32)
#define ROWT  32      // rows per tile
#define NBLOCKS 1250  // 6250 tiles / 5 per block
#define TPB   5       // tiles per block
#define EPSN  1e-12f

typedef __attribute__((ext_vector_type(8))) short short8;
typedef __attribute__((ext_vector_type(4))) float f32x4;

// ---------------- block-wide reductions -----------------------------------
__device__ __forceinline__ float blockReduceSum(float v, float* sbuf) {
  __syncthreads();
  #pragma unroll
  for (int o = 32; o > 0; o >>= 1) v += __shfl_down(v, o);
  int w = threadIdx.x >> 6;
  if ((threadIdx.x & 63) == 0) sbuf[w] = v;
  __syncthreads();
  if (threadIdx.x == 0) {
    float s = 0.f;
    int nw = blockDim.x >> 6;
    for (int i = 0; i < nw; ++i) s += sbuf[i];
    sbuf[0] = s;
  }
  __syncthreads();
  return sbuf[0];
}

__device__ __forceinline__ float blockReduceMax(float v, float* sbuf) {
  __syncthreads();
  #pragma unroll
  for (int o = 32; o > 0; o >>= 1) v = fmaxf(v, __shfl_down(v, o));
  int w = threadIdx.x >> 6;
  if ((threadIdx.x & 63) == 0) sbuf[w] = v;
  __syncthreads();
  if (threadIdx.x == 0) {
    float s = -FLT_MAX;
    int nw = blockDim.x >> 6;
    for (int i = 0; i < nw; ++i) s = fmaxf(s, sbuf[i]);
    sbuf[0] = s;
  }
  __syncthreads();
  return sbuf[0];
}

// ------------- top-k insert, list sorted (value desc, index asc) ----------
template<int T>
__device__ __forceinline__ void topk_insert(float v, int id, float (&lv)[T], int (&li)[T]) {
  if (!((v > lv[T-1]) || (v == lv[T-1] && id < li[T-1]))) return;
  #pragma unroll
  for (int p = T-1; p > 0; --p) {
    bool up = (v > lv[p-1]) || (v == lv[p-1] && id < li[p-1]);
    if (up) { lv[p] = lv[p-1]; li[p] = li[p-1]; }
    else    { lv[p] = v; li[p] = id; return; }
  }
  lv[0] = v; li[0] = id;
}

template<int T>
__device__ __forceinline__ void merge4(const float* sv, const int* si, int t,
                                       float* dv, int* di) {
  float fv[T]; int fi[T];
  #pragma unroll
  for (int i = 0; i < T; ++i) { fv[i] = -FLT_MAX; fi[i] = 0x7fffffff; }
  for (int s = 0; s < 4; ++s)
    #pragma unroll
    for (int i = 0; i < T; ++i)
      topk_insert<T>(sv[(t*4+s)*T+i], si[(t*4+s)*T+i], fv, fi);
  #pragma unroll
  for (int i = 0; i < T; ++i) { dv[t*T+i] = fv[i]; di[t*T+i] = fi[i]; }
}

// ---------------- rowmap fill ---------------------------------------------
__global__ void fill_rowmap(int* rowmap, int n) {
  int i = blockIdx.x * blockDim.x + threadIdx.x;
  if (i < n) rowmap[i] = -1;
}

// -------- prep: softmax, normalize queries -> MFMA A-frag pack, updates ---
__global__ __launch_bounds__(384) void prep_kernel(
    const float* __restrict__ tf, const float* __restrict__ fc1,
    const float* __restrict__ fc2, const int* __restrict__ idx,
    const float* __restrict__ featm, const float* __restrict__ fc1m,
    const float* __restrict__ fc2m,
    short* __restrict__ Qp_feat,   // [4][KSF][64][8] bf16 A-fragments
    short* __restrict__ Qp_fc1,    // [4][KSC][64][8]
    short* __restrict__ Qp_fc2,
    float* __restrict__ featU, float* __restrict__ fc1U, float* __restrict__ fc2U,
    int* __restrict__ rowmap)
{
  __shared__ float sbuf[8];
  const int b = blockIdx.x, t = threadIdx.x;
  const int trow = idx[b];
  const int qt = b >> 4, qr = b & 15;

  // ---- feature ----
  {
    float x = (t < DF) ? tf[b*DF + t] : 0.f;
    float ss = blockReduceSum(x*x, sbuf);
    float inv = 1.f / fmaxf(sqrtf(ss), EPSN);
    if (t < DF) {
      featU[b*DF + t] = 0.9f * featm[(size_t)trow*DF + t] + 0.1f * x;
      int ks = t >> 5, lg = (t >> 3) & 3, j = t & 7;
      int lane = qr + lg*16;
      union { __hip_bfloat16 h; short s; } cv;
      cv.h = __float2bfloat16(x * inv);
      Qp_feat[((qt*KSF + ks)*64 + lane)*8 + j] = cv.s;
    }
  }
  // ---- fc1 ----
  {
    float y = (t < CC) ? fc1[b*CC + t] : -FLT_MAX;
    float mx = blockReduceMax(y, sbuf);
    float e = (t < CC) ? expf(y - mx) : 0.f;
    float se = blockReduceSum(e, sbuf);
    float s = e / se;
    float s2 = blockReduceSum(s*s, sbuf);
    float inv2 = 1.f / fmaxf(sqrtf(s2), EPSN);
    if (t < CC) fc1U[b*CC + t] = 0.9f * fc1m[(size_t)trow*CC + t] + 0.1f * s;
    if (t < KSC*32) {
      int ks = t >> 5, lg = (t >> 3) & 3, j = t & 7;
      int lane = qr + lg*16;
      union { __hip_bfloat16 h; short s; } cv;
      cv.h = __float2bfloat16((t < CC) ? s * inv2 : 0.f);
      Qp_fc1[((qt*KSC + ks)*64 + lane)*8 + j] = cv.s;
    }
  }
  // ---- fc2 ----
  {
    float y = (t < CC) ? fc2[b*CC + t] : -FLT_MAX;
    float mx = blockReduceMax(y, sbuf);
    float e = (t < CC) ? expf(y - mx) : 0.f;
    float se = blockReduceSum(e, sbuf);
    float s = e / se;
    float s2 = blockReduceSum(s*s, sbuf);
    float inv2 = 1.f / fmaxf(sqrtf(s2), EPSN);
    if (t < CC) fc2U[b*CC + t] = 0.9f * fc2m[(size_t)trow*CC + t] + 0.1f * s;
    if (t < KSC*32) {
      int ks = t >> 5, lg = (t >> 3) & 3, j = t & 7;
      int lane = qr + lg*16;
      union { __hip_bfloat16 h; short s; } cv;
      cv.h = __float2bfloat16((t < CC) ? s * inv2 : 0.f);
      Qp_fc2[((qt*KSC + ks)*64 + lane)*8 + j] = cv.s;
    }
  }
  if (t == 0) rowmap[trow] = b;
}

// -------- staged MFMA cos-sim: linear coalesced loads -> bf16 LDS ---------
// 32 rows/tile, double-buffered; fused per-thread topk across tiles.
// CORR=false: main banks, rows with rowmap>=0 masked out.
// CORR=true : 64-row updated bank, ids[] remaps local row -> true row id.
template<int D, int KS, int T, bool CORR>
__global__ __launch_bounds__(256) void dist_topk2(
    const float* __restrict__ bank,
    const int* __restrict__ rowmap,
    const int* __restrict__ ids,
    const short8* __restrict__ Qp,
    float* __restrict__ cand_v, int* __restrict__ cand_i,
    int ntiles, int cand_cols)
{
  constexpr int RB      = D * 4;            // row bytes (f32)
  constexpr int TILE_B  = ROWT * RB;        // tile bytes
  constexpr int CHUNKS  = TILE_B / 16;      // 16B chunks per tile
  constexpr int CPI     = (CHUNKS + 255) / 256;
  constexpr int SCH     = (D == 256) ? 33 : 45;  // 16B chunks per LDS row (odd!)
  constexpr int KPAD    = KS * 32;
  constexpr int BUFB    = ROWT * SCH * 16;  // bytes per buffer

  __shared__ __align__(16) char smem[2*BUFB + 64*35*4 + 128];
  char*  bufc = smem;
  float* sims = (float*)(smem + 2*BUFB);
  float* rinv = (float*)(smem + 2*BUFB + 64*35*4);
  float* mv   = (float*)smem;               // aliased after loop
  int*   mi   = (int*)(smem + 256*T*4);

  const int t  = threadIdx.x;
  const int l  = t & 63, w = t >> 6;
  const int lc = l & 15, lg = l >> 4;

  // staging chunk -> (row,col) decomposition (tile-invariant)
  int rc_r[CPI], rc_c[CPI];
  #pragma unroll
  for (int i = 0; i < CPI; ++i) {
    int f0 = (t + 256*i) * 4;
    int r = f0 / D;
    rc_r[i] = r; rc_c[i] = f0 - r*D;
  }

  // A fragments (this wave's 16 queries)
  short8 afr[KS];
  #pragma unroll
  for (int ks = 0; ks < KS; ++ks) afr[ks] = Qp[(w*KS + ks)*64 + l];

  // zero padded cols (D..KPAD) once, both buffers
  if (KPAD > D) {
    for (int z = t; z < 2*ROWT*(KPAD - D); z += 256) {
      int b  = z / (ROWT*(KPAD - D));
      int zz = z % (ROWT*(KPAD - D));
      int rr = zz / (KPAD - D);
      int cc2 = D + zz % (KPAD - D);
      *((__hip_bfloat16*)(bufc + b*BUFB + rr*SCH*16) + cc2) = __float2bfloat16(0.f);
    }
  }

  float lv[T]; int li[T];
  #pragma unroll
  for (int i = 0; i < T; ++i) { lv[i] = -FLT_MAX; li[i] = 0x7fffffff; }

  const int first_tile = CORR ? 0 : blockIdx.x * TPB;
  float4 ld[CPI];

  auto ISSUE = [&](int tile) {
    const char* tb = (const char*)bank + (size_t)tile * TILE_B;
    #pragma unroll
    for (int i = 0; i < CPI; ++i) {
      int c = t + 256*i;
      if (c < CHUNKS) ld[i] = *(const float4*)(tb + (size_t)c*16);
    }
  };
  auto WRITE = [&](int b) {
    char* bb = bufc + b*BUFB;
    #pragma unroll
    for (int i = 0; i < CPI; ++i) {
      int c = t + 256*i;
      if (c < CHUNKS) {
        float vv[4] = {ld[i].x, ld[i].y, ld[i].z, ld[i].w};
        #pragma unroll
        for (int j = 0; j < 4; ++j) {
          int row = rc_r[i], col = rc_c[i] + j;
          if (col >= D) { col -= D; row += 1; }
          *((__hip_bfloat16*)(bb + row*SCH*16) + col) = __float2bfloat16(vv[j]);
        }
      }
    }
  };

  // prologue
  ISSUE(first_tile);
  WRITE(0);
  __syncthreads();

  for (int it = 0; it < ntiles; ++it) {
    const int cur = it & 1;
    if (it + 1 < ntiles) ISSUE(first_tile + it + 1);

    const char* bb = bufc + cur*BUFB;

    // row inverse-norms from staged bf16
    {
      int r = t >> 3, e = t & 7;
      float s = 0.f;
      #pragma unroll
      for (int k2 = 0; k2 < (SCH - 1 + 7)/8; ++k2) {
        int ci = e + 8*k2;
        if (ci < SCH - 1) {
          short8 h = *(const short8*)(bb + r*SCH*16 + ci*16);
          #pragma unroll
          for (int j = 0; j < 8; ++j) {
            float f = __uint_as_float(((unsigned)(unsigned short)h[j]) << 16);
            s += f * f;
          }
        }
      }
      s += __shfl_xor(s, 1);
      s += __shfl_xor(s, 2);
      s += __shfl_xor(s, 4);
      if (e == 0) rinv[r] = 1.f / fmaxf(sqrtf(s), EPSN);
    }

    // MFMA: 16 queries (wave) x 32 rows
    f32x4 acc[2];
    acc[0] = (f32x4){0.f,0.f,0.f,0.f};
    acc[1] = (f32x4){0.f,0.f,0.f,0.f};
    #pragma unroll
    for (int ks = 0; ks < KS; ++ks) {
      #pragma unroll
      for (int rt = 0; rt < 2; ++rt) {
        int row = rt*16 + lc;
        short8 bf = *(const short8*)(bb + row*SCH*16 + (ks*4 + lg)*16);
        acc[rt] = __builtin_amdgcn_mfma_f32_16x16x32_bf16(afr[ks], bf, acc[rt], 0, 0, 0);
      }
    }
    #pragma unroll
    for (int rt = 0; rt < 2; ++rt)
      #pragma unroll
      for (int rg = 0; rg < 4; ++rg)
        sims[(w*16 + lg*4 + rg)*35 + rt*16 + lc] = acc[rt][rg];

    __syncthreads();

    // fused topk: 4 threads per query, 8 rows each
    {
      int q = t & 63, sub = t >> 6;
      int gbase = (first_tile + it) * ROWT;
      #pragma unroll
      for (int j = 0; j < 8; ++j) {
        int rl = sub*8 + j;
        float v = sims[q*35 + rl] * rinv[rl];
        int gl = gbase + rl;
        if (CORR) topk_insert<T>(v, ids[gl], lv, li);
        else if (rowmap[gl] < 0) topk_insert<T>(v, gl, lv, li);
      }
    }

    if (it + 1 < ntiles) WRITE(cur ^ 1);
    __syncthreads();
  }

  // block-level merge (4 sublists per query) -> candidate slot
  #pragma unroll
  for (int i = 0; i < T; ++i) { mv[t*T + i] = lv[i]; mi[t*T + i] = li[i]; }
  __syncthreads();
  if (t < 64) {
    float fv[T]; int fi[T];
    #pragma unroll
    for (int i = 0; i < T; ++i) { fv[i] = -FLT_MAX; fi[i] = 0x7fffffff; }
    for (int s = 0; s < 4; ++s) {
      int src = t + 64*s;
      #pragma unroll
      for (int i = 0; i < T; ++i)
        topk_insert<T>(mv[src*T + i], mi[src*T + i], fv, fi);
    }
    int slot = CORR ? (cand_cols - 1) : blockIdx.x;
    size_t base = ((size_t)t * cand_cols + slot) * T;
    #pragma unroll
    for (int i = 0; i < T; ++i) { cand_v[base + i] = fv[i]; cand_i[base + i] = fi[i]; }
  }
}

// -------- hierarchical merge: block candidates -> global top-T per query --
template<int T>
__global__ __launch_bounds__(256) void merge_topk(
    const float* __restrict__ cv, const int* __restrict__ ci,
    int nc, int* __restrict__ topout)      // topout stride 6
{
  __shared__ float sv[256*T]; __shared__ int si[256*T];
  __shared__ float sv2[64*T]; __shared__ int si2[64*T];
  const int q = blockIdx.x, t = threadIdx.x;
  float lv[T]; int li[T];
  #pragma unroll
  for (int i = 0; i < T; ++i) { lv[i] = -FLT_MAX; li[i] = 0x7fffffff; }
  const float* v  = cv + (size_t)q * nc;
  const int*   ii = ci + (size_t)q * nc;
  for (int c = t; c < nc; c += 256) topk_insert<T>(v[c], ii[c], lv, li);
  #pragma unroll
  for (int i = 0; i < T; ++i) { sv[t*T+i] = lv[i]; si[t*T+i] = li[i]; }
  __syncthreads();
  if (t < 64) merge4<T>(sv, si, t, sv2, si2);
  __syncthreads();
  if (t < 16) merge4<T>(sv2, si2, t, sv, si);
  __syncthreads();
  if (t < 4)  merge4<T>(sv, si, t, sv2, si2);
  __syncthreads();
  if (t == 0) {
    float fv[T]; int fi[T];
    #pragma unroll
    for (int i = 0; i < T; ++i) { fv[i] = -FLT_MAX; fi[i] = 0x7fffffff; }
    for (int s = 0; s < 4; ++s)
      #pragma unroll
      for (int i = 0; i < T; ++i)
        topk_insert<T>(sv2[s*T+i], si2[s*T+i], fv, fi);
    #pragma unroll
    for (int i = 0; i < T; ++i) topout[q*6 + i] = fi[i];
  }
}

// ---------------- losses ---------------------------------------------------
__global__ __launch_bounds__(384) void loss_softmax_kernel(
    const int* __restrict__ topfeat, const int* __restrict__ rowmap,
    const float* __restrict__ fc1m, const float* __restrict__ fc1U,
    const float* __restrict__ fc2m, const float* __restrict__ fc2U,
    float* __restrict__ out)
{
  __shared__ float sbuf[8];
  int p = blockIdx.x;                // 0..319
  int q = p / 5, j = p % 5 + 1;
  int row = topfeat[q*6 + j];
  int u = rowmap[row];
  const float* r1 = (u >= 0) ? (fc1U + (size_t)u * CC) : (fc1m + (size_t)row * CC);
  const float* r2 = (u >= 0) ? (fc2U + (size_t)u * CC) : (fc2m + (size_t)row * CC);
  int t = threadIdx.x;
  float v = (t < CC) ? fabsf(r1[t] - r2[t]) : 0.f;
  float s = blockReduceSum(v, sbuf);
  if (t == 0) atomicAdd(out, s * (1.f / (320.f * 345.f)));
}

__global__ __launch_bounds__(256) void loss_feature_kernel(
    const int* __restrict__ topfc1, const int* __restrict__ topfc2,
    const int* __restrict__ rowmap, const float* __restrict__ featm,
    const float* __restrict__ featU, float* __restrict__ out)
{
  __shared__ float sbuf[8];
  int p = blockIdx.x;                // 0..255
  int q = p / 4, j = p % 4 + 1;
  int ra = topfc1[q*6 + j], rb = topfc2[q*6 + j];
  int ua = rowmap[ra], ub = rowmap[rb];
  const float* A  = (ua >= 0) ? (featU + (size_t)ua * DF) : (featm + (size_t)ra * DF);
  const float* Bp = (ub >= 0) ? (featU + (size_t)ub * DF) : (featm + (size_t)rb * DF);
  int t = threadIdx.x;               // 256 == DF
  float a = A[t], b = Bp[t];
  float saa = blockReduceSum(a*a, sbuf);
  float sbb = blockReduceSum(b*b, sbuf);
  float sab = blockReduceSum(a*b, sbuf);
  if (t == 0) {
    float fd = 0.5f * (1.f - sab / (fmaxf(sqrtf(saa), EPSN) * fmaxf(sqrtf(sbb), EPSN)));
    atomicAdd(out + 1, fd * (1.f / 256.f));
  }
}

// ---------------- launch ---------------------------------------------------
extern "C" void kernel_launch(void* const* d_in, const int* in_sizes, int n_in,
                              void* d_out, int out_size, void* d_ws, size_t ws_size,
                              hipStream_t stream)
{
  const float* tf    = (const float*)d_in[0];
  const float* fc1   = (const float*)d_in[1];
  const float* fc2   = (const float*)d_in[2];
  const int*   idx   = (const int*)d_in[3];
  const float* featm = (const float*)d_in[4];
  const float* fc1m  = (const float*)d_in[5];
  const float* fc2m  = (const float*)d_in[6];
  float* out = (float*)d_out;

  const int N = in_sizes[4] / DF;      // 200000
  const int CAND_COLS = NBLOCKS + 1;   // +1 slot for correction kernel

  char* w = (char*)d_ws;
  auto alloc = [&](size_t bytes) {
    char* p = w;
    w += (bytes + 255) & ~(size_t)255;
    return (void*)p;
  };
  short* Qp_feat = (short*)alloc((size_t)4 * KSF * 64 * 8 * 2);
  short* Qp_fc1  = (short*)alloc((size_t)4 * KSC * 64 * 8 * 2);
  short* Qp_fc2  = (short*)alloc((size_t)4 * KSC * 64 * 8 * 2);
  float* featU   = (float*)alloc((size_t)NQ * DF * 4);
  float* fc1U    = (float*)alloc((size_t)NQ * CC * 4);
  float* fc2U    = (float*)alloc((size_t)NQ * CC * 4);
  int*   rowmap  = (int*)alloc((size_t)N * 4);
  int*   topfeat = (int*)alloc(NQ * 6 * 4);
  int*   topfc1  = (int*)alloc(NQ * 6 * 4);
  int*   topfc2  = (int*)alloc(NQ * 6 * 4);
  float* cand_v  = (float*)alloc((size_t)NQ * CAND_COLS * 6 * 4);
  int*   cand_i  = (int*)alloc((size_t)NQ * CAND_COLS * 6 * 4);

  hipMemsetAsync(d_out, 0, 2 * sizeof(float), stream);
  fill_rowmap<<<(N + 255) / 256, 256, 0, stream>>>(rowmap, N);
  prep_kernel<<<NQ, 384, 0, stream>>>(tf, fc1, fc2, idx, featm, fc1m, fc2m,
      Qp_feat, Qp_fc1, Qp_fc2, featU, fc1U, fc2U, rowmap);

  // feature: top-6 (drop first, keep 5)
  dist_topk2<DF, KSF, 6, false><<<NBLOCKS, 256, 0, stream>>>(
      featm, rowmap, idx, (const short8*)Qp_feat, cand_v, cand_i, TPB, CAND_COLS);
  dist_topk2<DF, KSF, 6, true><<<1, 256, 0, stream>>>(
      featU, rowmap, idx, (const short8*)Qp_feat, cand_v, cand_i, 2, CAND_COLS);
  merge_topk<6><<<NQ, 256, 0, stream>>>(cand_v, cand_i, CAND_COLS * 6, topfeat);

  // fc1: top-5 (drop first, keep 4)
  dist_topk2<CC, KSC, 5, false><<<NBLOCKS, 256, 0, stream>>>(
      fc1m, rowmap, idx, (const short8*)Qp_fc1, cand_v, cand_i, TPB, CAND_COLS);
  dist_topk2<CC, KSC, 5, true><<<1, 256, 0, stream>>>(
      fc1U, rowmap, idx, (const short8*)Qp_fc1, cand_v, cand_i, 2, CAND_COLS);
  merge_topk<5><<<NQ, 256, 0, stream>>>(cand_v, cand_i, CAND_COLS * 5, topfc1);

  // fc2: top-5
  dist_topk2<CC, KSC, 5, false><<<NBLOCKS, 256, 0, stream>>>(
      fc2m, rowmap, idx, (const short8*)Qp_fc2, cand_v, cand_i, TPB, CAND_COLS);
  dist_topk2<CC, KSC, 5, true><<<1, 256, 0, stream>>>(
      fc2U, rowmap, idx, (const short8*)Qp_fc2, cand_v, cand_i, 2, CAND_COLS);
  merge_topk<5><<<NQ, 256, 0, stream>>>(cand_v, cand_i, CAND_COLS * 5, topfc2);

  loss_softmax_kernel<<<320, 384, 0, stream>>>(topfeat, rowmap, fc1m, fc1U, fc2m, fc2U, out);
  loss_feature_kernel<<<256, 256, 0, stream>>>(topfc1, topfc2, rowmap, featm, featU, out);
}